// Round 7
// baseline (276.825 us; speedup 1.0000x reference)
//
#include <hip/hip_runtime.h>

#define VOL   2097152          // 128*128*128
#define TBL   4194304          // BATCH * VOL
#define D1D2  16384
#define DD2   128
#define TILE  128

typedef __bf16 bf16_t;
typedef bf16_t bf16x8 __attribute__((ext_vector_type(8)));
typedef float  floatx16 __attribute__((ext_vector_type(16)));

// ---------------- prep: table scatter + range counts + weight relayout ----
// table AND rc are memset to 0xFF (-1) before this dispatch.
// rc[r] ends at (count-1); readers add +1.

__global__ __launch_bounds__(256) void prep_k(const float* __restrict__ w,
                                              const int* __restrict__ idx,
                                              int* __restrict__ table,
                                              int* __restrict__ rc,
                                              bf16_t* __restrict__ wb, int n) {
    const int b = blockIdx.x;
    const int tblB = (n + 255) >> 8;
    if (b < tblB) {
        int t = b * 256 + threadIdx.x;
        if (t < n) {
            int4 c = ((const int4*)idx)[t];                 // b, i0, i1, i2
            int p = ((c.x * 128 + c.y) * 128 + c.z) * 128 + c.w;
            table[p] = t;                                   // original voxel id
            atomicAdd(&rc[p >> 12], 1);                     // 4096-slot range count
        }
    } else {
        int t = (b - tblB) * 256 + threadIdx.x;
        if (t < 27 * 64 * 64) {
            // wb layout: [tap][cb 0..7][co 0..63][j 0..7], element = W[co][tap][cb*8+j]
            int j = t & 7, co = (t >> 3) & 63, cb = (t >> 9) & 7, tap = t >> 12;
            wb[t] = (bf16_t)w[(co * 27 + tap) * 64 + cb * 8 + j];
        }
    }
}

// ---------------- compact: inline prefix + scan + feature gather-convert --
// Each block owns 4096 consecutive packed slots. Deterministic order.

__global__ __launch_bounds__(256) void compact_k(const float* __restrict__ f,
                                                 int* __restrict__ table,
                                                 const int* __restrict__ rc,
                                                 int* __restrict__ ord,
                                                 int* __restrict__ pkd,
                                                 bf16_t* __restrict__ fbp) {
    __shared__ int s_red[256];
    __shared__ int s_cnt[256];
    __shared__ int s_orig[4096];
    const int t   = threadIdx.x;
    const int bid = blockIdx.x;

    // global base = prefix sum of range counts (rc[i]+1 due to -1 init)
    int part = 0;
    for (int i = t; i < bid; i += 256) part += rc[i] + 1;
    s_red[t] = part;
    __syncthreads();
    for (int off = 128; off; off >>= 1) {
        if (t < off) s_red[t] += s_red[t + off];
        __syncthreads();
    }
    const int rbase = s_red[0];

    const int base = bid * 4096 + t * 16;
    int v[16];
    #pragma unroll
    for (int i = 0; i < 4; ++i)
        *(int4*)&v[i * 4] = ((const int4*)(table + base))[i];
    int cnt = 0;
    #pragma unroll
    for (int i = 0; i < 16; ++i) cnt += (v[i] >= 0);

    s_cnt[t] = cnt;
    __syncthreads();
    int x = cnt;                                // inclusive scan (round-6 proven)
    for (int off = 1; off < 256; off <<= 1) {
        int y = (t >= off) ? s_cnt[t - off] : 0;
        __syncthreads();
        x += y;
        s_cnt[t] = x;
        __syncthreads();
    }

    int lp = x - cnt;                           // local exclusive offset
    int pos = rbase + lp;
    #pragma unroll
    for (int i = 0; i < 16; ++i) {
        if (v[i] >= 0) {
            ord[pos] = v[i];
            pkd[pos] = base + i;
            table[base + i] = pos;
            s_orig[lp] = v[i];
            ++lp; ++pos;
        }
    }
    __syncthreads();                            // s_orig + s_cnt[255] ready

    // fused feature permute+convert for this block's voxels (consecutive pos)
    const int total = s_cnt[255];
    for (int u = t; u < total * 8; u += 256) {
        int vox = u >> 3, c = (u & 7) * 8;
        int orig = s_orig[vox];
        const float* src = f + (size_t)orig * 64 + c;
        float4 a  = *(const float4*)src;
        float4 b2 = *(const float4*)(src + 4);
        bf16x8 o = { (bf16_t)a.x,  (bf16_t)a.y,  (bf16_t)a.z,  (bf16_t)a.w,
                     (bf16_t)b2.x, (bf16_t)b2.y, (bf16_t)b2.z, (bf16_t)b2.w };
        *(bf16x8*)(fbp + (size_t)(rbase + vox) * 64 + c) = o;
    }
}

// ---------------- main conv kernel ----------------
// block = 256 thr (4 waves); tile = 128 voxels (compacted) x 64 out-ch
// mfma_f32_32x32x16_bf16. Wave w: co-tile ct=w&1 (32 co), voxel half vh=(w>>1)*64
// (2 voxel-tiles of 32). A (weights) from global (L1-resident), B from LDS.
// C/D: col(n=vox)=lane&31, row(m=co)=(reg&3)+8*(reg>>2)+4*(lane>>5)  (m74/m101)

__global__ __launch_bounds__(256) void conv_k(
        const bf16_t* __restrict__ fbp, const bf16_t* __restrict__ wb,
        const int* __restrict__ table, const int* __restrict__ pkd,
        const int* __restrict__ ord, const float* __restrict__ bias,
        float* __restrict__ out, int n)
{
    __shared__ int    s_pkd[TILE];
    __shared__ int    s_ord[TILE];
    __shared__ int    s_nbr[27 * TILE];
    __shared__ bf16_t sF[TILE * 72];      // gathered features (pad 64->72)

    const int t  = threadIdx.x;
    int bidx = blockIdx.x;                // XCD swizzle: contiguous chunk per XCD
    int gb = gridDim.x;
    if ((gb & 7) == 0) bidx = (bidx & 7) * (gb >> 3) + (bidx >> 3);
    const int tile = bidx * TILE;

    if (t < TILE) {
        int vn = tile + t;
        s_pkd[t] = (vn < n) ? pkd[vn] : (int)0xC0000000;  // sentinel: taps miss
        s_ord[t] = (vn < n) ? ord[vn] : 0;
    }
    __syncthreads();

    for (int u = t; u < 27 * TILE; u += 256) {
        int k  = u >> 7;                  // TILE == 128
        int r  = u & (TILE - 1);
        int k0 = k / 9, k1 = (k / 3) % 3, k2 = k % 3;
        int np = s_pkd[r] + (k0 - 1) * D1D2 + (k1 - 1) * DD2 + (k2 - 1);
        s_nbr[u] = (np >= 0 && np < TBL) ? table[np] : -1;
    }

    const int lane = t & 63;
    const int w    = t >> 6;
    const int ct   = w & 1;               // co-tile (32 co)
    const int vh   = (w >> 1) * 64;       // voxel-half base
    const int l31  = lane & 31;
    const int h    = lane >> 5;           // half-wave

    const int rF = t >> 1;                // staging: feature row 0..127
    const int hF = t & 1;                 // half-row (32 ch)

    floatx16 acc0 = {}, acc1 = {};

    __syncthreads();                      // s_nbr ready

    // prefetch tap 0: features + A-frags
    bf16x8 pf[4] = {{}, {}, {}, {}};
    bf16x8 pa[4];
    {
        int nbr = s_nbr[rF];
        if (nbr >= 0) {
            const bf16x8* src = (const bf16x8*)(fbp + (size_t)nbr * 64 + hF * 32);
            pf[0] = src[0]; pf[1] = src[1]; pf[2] = src[2]; pf[3] = src[3];
        }
        #pragma unroll
        for (int ks = 0; ks < 4; ++ks)
            pa[ks] = *(const bf16x8*)(wb + ((ks * 2 + h) * 64 + ct * 32 + l31) * 8);
    }

    for (int k = 0; k < 27; ++k) {
        // commit prefetched features to LDS
        *(bf16x8*)&sF[rF * 72 + hF * 32]      = pf[0];
        *(bf16x8*)&sF[rF * 72 + hF * 32 + 8]  = pf[1];
        *(bf16x8*)&sF[rF * 72 + hF * 32 + 16] = pf[2];
        *(bf16x8*)&sF[rF * 72 + hF * 32 + 24] = pf[3];

        // issue tap k+1 loads
        bf16x8 nf[4] = {{}, {}, {}, {}};
        bf16x8 na[4];
        const bool more = (k + 1 < 27);
        if (more) {
            int nbr = s_nbr[(k + 1) * TILE + rF];
            if (nbr >= 0) {
                const bf16x8* src = (const bf16x8*)(fbp + (size_t)nbr * 64 + hF * 32);
                nf[0] = src[0]; nf[1] = src[1]; nf[2] = src[2]; nf[3] = src[3];
            }
            #pragma unroll
            for (int ks = 0; ks < 4; ++ks)
                na[ks] = *(const bf16x8*)(wb +
                          (((k + 1) * 8 + ks * 2 + h) * 64 + ct * 32 + l31) * 8);
        }

        __syncthreads();                  // staging visible

        #pragma unroll
        for (int ks = 0; ks < 4; ++ks) {
            bf16x8 a  = pa[ks];
            bf16x8 b0 = *(const bf16x8*)&sF[(vh + l31) * 72      + ks * 16 + h * 8];
            bf16x8 b1 = *(const bf16x8*)&sF[(vh + 32 + l31) * 72 + ks * 16 + h * 8];
            acc0 = __builtin_amdgcn_mfma_f32_32x32x16_bf16(a, b0, acc0, 0, 0, 0);
            acc1 = __builtin_amdgcn_mfma_f32_32x32x16_bf16(a, b1, acc1, 0, 0, 0);
        }

        __syncthreads();                  // MFMA reads done before next write

        if (more) {
            #pragma unroll
            for (int i = 0; i < 4; ++i) { pf[i] = nf[i]; pa[i] = na[i]; }
        }
    }

    // epilogue: co = ct*32 + 4h + 8*rg + rr  (rg=reg>>2, rr=reg&3)
    float4 b4[4];
    #pragma unroll
    for (int rg = 0; rg < 4; ++rg)
        b4[rg] = *(const float4*)&bias[ct * 32 + h * 4 + rg * 8];

    #pragma unroll
    for (int vt = 0; vt < 2; ++vt) {
        int vl = vh + vt * 32 + l31;
        int vn = tile + vl;
        if (vn < n) {
            int orig = s_ord[vl];
            float* dst = out + (size_t)orig * 64 + ct * 32 + h * 4;
            floatx16 A = vt ? acc1 : acc0;
            #pragma unroll
            for (int rg = 0; rg < 4; ++rg) {
                float4 o;
                o.x = A[rg * 4 + 0] + b4[rg].x;
                o.y = A[rg * 4 + 1] + b4[rg].y;
                o.z = A[rg * 4 + 2] + b4[rg].z;
                o.w = A[rg * 4 + 3] + b4[rg].w;
                *(float4*)(dst + rg * 8) = o;
            }
        }
    }
}

// ---------------- launch ----------------

extern "C" void kernel_launch(void* const* d_in, const int* in_sizes, int n_in,
                              void* d_out, int out_size, void* d_ws, size_t ws_size,
                              hipStream_t stream) {
    const float* feat = (const float*)d_in[0];
    const float* wgt  = (const float*)d_in[1];
    const float* bias = (const float*)d_in[2];
    const int*   idx  = (const int*)d_in[3];
    float* out = (float*)d_out;

    const int n = in_sizes[0] / 64;          // active voxels

    // ws: [table 16MB][rc 4KB][wb 256KB][fbp 33.5MB][ord][pkd]  (= round-6 proven size)
    char* ws = (char*)d_ws;
    int*    table = (int*)ws;
    int*    rc    = (int*)(ws + (size_t)TBL * 4);
    bf16_t* wbf   = (bf16_t*)(ws + (size_t)TBL * 4 + 4096);
    bf16_t* fbp   = (bf16_t*)(ws + (size_t)TBL * 4 + 4096 + 262144);
    int*    ord   = (int*)(ws + (size_t)TBL * 4 + 4096 + 262144 + (size_t)n * 128);
    int*    pkd   = ord + n;

    // one memset covers table AND rc with -1
    hipMemsetAsync(table, 0xFF, (size_t)TBL * 4 + 4096, stream);

    int tblB = (n + 255) >> 8;
    prep_k<<<tblB + 432, 256, 0, stream>>>(wgt, idx, table, rc, wbf, n);
    compact_k<<<1024, 256, 0, stream>>>(feat, table, rc, ord, pkd, fbp);
    conv_k<<<(n + TILE - 1) / TILE, 256, 0, stream>>>(fbp, wbf, table, pkd, ord, bias, out, n);
}